// Round 1
// baseline (445.173 us; speedup 1.0000x reference)
//
#include <hip/hip_runtime.h>

#define IN_CH 128
#define HID 64
#define NEG 0.2f

// ---------------- K1: projections xl = x@W_l.T, xr = x@W_r.T ----------------
// Two phases (W_l then W_r), W staged in LDS padded stride 132 (float4 reads,
// bank-conflict-free: (132c+k)%32 covers all banks across lanes).
__global__ __launch_bounds__(256) void proj_kernel(
    const float* __restrict__ x, const float* __restrict__ W_l,
    const float* __restrict__ W_r,
    float* __restrict__ xl, float* __restrict__ xr, int nN)
{
    __shared__ float Ws[64 * 132];
    __shared__ float x_s[4 * IN_CH];
    int tid = threadIdx.x;
    int lane = tid & 63, w = tid >> 6;

    for (int m = 0; m < 2; ++m) {
        const float* __restrict__ W = m ? W_r : W_l;
        float* __restrict__ dstv = m ? xr : xl;
        __syncthreads();  // protect Ws from previous phase readers
        for (int idx = tid; idx < 64 * IN_CH; idx += 256) {
            int c = idx >> 7, k = idx & 127;
            Ws[c * 132 + k] = W[idx];
        }
        __syncthreads();
        for (int nb = blockIdx.x * 4; nb < nN; nb += gridDim.x * 4) {
            int node = nb + w;
            if (node < nN) {
                float2 xv = *(const float2*)(x + (size_t)node * IN_CH + lane * 2);
                x_s[w * IN_CH + lane * 2]     = xv.x;
                x_s[w * IN_CH + lane * 2 + 1] = xv.y;
            }
            __syncthreads();
            if (node < nN) {
                float acc = 0.f;
                const float4* xs4 = (const float4*)(x_s + w * IN_CH);
                const float4* w4  = (const float4*)(Ws + lane * 132);
                #pragma unroll 8
                for (int k4 = 0; k4 < 32; ++k4) {
                    float4 xv = xs4[k4];
                    float4 wv = w4[k4];
                    acc = fmaf(xv.x, wv.x, acc);
                    acc = fmaf(xv.y, wv.y, acc);
                    acc = fmaf(xv.z, wv.z, acc);
                    acc = fmaf(xv.w, wv.w, acc);
                }
                dstv[(size_t)node * HID + lane] = acc;
            }
            __syncthreads();
        }
    }
}

// ---------------- K2: in-degree histogram ----------------
__global__ __launch_bounds__(256) void hist_kernel(
    const int* __restrict__ dst, int* __restrict__ deg, int E)
{
    int i = blockIdx.x * 256 + threadIdx.x;
    if (i < E) atomicAdd(&deg[dst[i]], 1);
}

// ---------------- K3: exclusive scan (single block, int4 chunks of 4096) ----
__global__ __launch_bounds__(1024) void scan_kernel(
    const int* __restrict__ deg, int* __restrict__ row_start,
    int* __restrict__ cursor, int np)
{
    __shared__ int wsum[16];
    __shared__ int running_s;
    int tid = threadIdx.x, lane = tid & 63, w = tid >> 6;
    if (tid == 0) running_s = 0;
    __syncthreads();
    for (int base = 0; base < np; base += 4096) {
        int i = base + tid * 4;
        int4 v = *(const int4*)(deg + i);
        int p0 = v.x, p1 = p0 + v.y, p2 = p1 + v.z, p3 = p2 + v.w;
        int sv = p3;
        for (int d = 1; d < 64; d <<= 1) {
            int t = __shfl_up(sv, d, 64);
            if (lane >= d) sv += t;
        }
        if (lane == 63) wsum[w] = sv;
        __syncthreads();
        if (tid < 16) {
            int t = wsum[tid];
            for (int d = 1; d < 16; d <<= 1) {
                int u = __shfl_up(t, d, 64);
                if (tid >= d) t += u;
            }
            wsum[tid] = t;
        }
        __syncthreads();
        int run0 = running_s;
        int excl = run0 + (w ? wsum[w - 1] : 0) + sv - p3;  // thread-exclusive
        int4 o = make_int4(excl, excl + p0, excl + p1, excl + p2);
        *(int4*)(row_start + i) = o;
        *(int4*)(cursor + i) = o;
        __syncthreads();
        if (tid == 0) running_s = run0 + wsum[15];
        __syncthreads();
    }
}

// ---------------- K4: scatter edges into CSR slots ----------------
__global__ __launch_bounds__(256) void scatter_kernel(
    const int* __restrict__ src, const int* __restrict__ dst,
    int* __restrict__ cursor, int* __restrict__ csr, int E)
{
    int i = blockIdx.x * 256 + threadIdx.x;
    if (i < E) {
        int p = atomicAdd(&cursor[dst[i]], 1);
        csr[p] = src[i];
    }
}

// ---------------- K5: fused attention + aggregation + ELU + linear ----------
// One wave per node (lane = channel). After scatter, cursor[i] == row end.
__global__ __launch_bounds__(256) void gat_main(
    const float* __restrict__ xl, const float* __restrict__ xr,
    const int* __restrict__ row_start, const int* __restrict__ row_end,
    const int* __restrict__ csr,
    const float* __restrict__ att, const float* __restrict__ bias_conv,
    const float* __restrict__ W_lin, const float* __restrict__ b_lin,
    float* __restrict__ out, int nN)
{
    __shared__ float WT[64 * 65];   // WT[c*65+o] = W_lin[o][c], +1 pad
    __shared__ float hbuf[4][64];
    int tid = threadIdx.x;
    for (int idx = tid; idx < 64 * 64; idx += 256) {
        int o = idx >> 6, c = idx & 63;
        WT[c * 65 + o] = W_lin[idx];
    }
    __syncthreads();
    int lane = tid & 63, w = tid >> 6;
    int node = blockIdx.x * 4 + w;
    bool active = node < nN;
    float h = 0.f;
    if (active) {
        float att_v = att[lane];
        float xr_v  = xr[(size_t)node * HID + lane];
        // self loop (j = node)
        float xls = xl[(size_t)node * HID + lane];
        float t = xls + xr_v;
        float lr = fmaxf(t, 0.f) + NEG * fminf(t, 0.f);
        float r = att_v * lr;
        #pragma unroll
        for (int off = 32; off; off >>= 1) r += __shfl_xor(r, off, 64);
        float ev = __expf(r);
        float denom = ev;
        float acc = ev * xls;
        int s = row_start[node], e = row_end[node];
        int k = s;
        for (; k + 1 < e; k += 2) {
            int j0 = csr[k], j1 = csr[k + 1];
            float x0 = xl[(size_t)j0 * HID + lane];
            float x1 = xl[(size_t)j1 * HID + lane];
            float t0 = x0 + xr_v, t1 = x1 + xr_v;
            float l0 = fmaxf(t0, 0.f) + NEG * fminf(t0, 0.f);
            float l1 = fmaxf(t1, 0.f) + NEG * fminf(t1, 0.f);
            float r0 = att_v * l0, r1 = att_v * l1;
            #pragma unroll
            for (int off = 32; off; off >>= 1) {
                r0 += __shfl_xor(r0, off, 64);
                r1 += __shfl_xor(r1, off, 64);
            }
            float e0 = __expf(r0), e1 = __expf(r1);
            denom += e0 + e1;
            acc = fmaf(e0, x0, acc);
            acc = fmaf(e1, x1, acc);
        }
        if (k < e) {
            int j0 = csr[k];
            float x0 = xl[(size_t)j0 * HID + lane];
            float t0 = x0 + xr_v;
            float l0 = fmaxf(t0, 0.f) + NEG * fminf(t0, 0.f);
            float r0 = att_v * l0;
            #pragma unroll
            for (int off = 32; off; off >>= 1) r0 += __shfl_xor(r0, off, 64);
            float e0 = __expf(r0);
            denom += e0;
            acc = fmaf(e0, x0, acc);
        }
        h = acc / (denom + 1e-16f) + bias_conv[lane];
        h = (h > 0.f) ? h : (__expf(h) - 1.f);   // ELU
    }
    hbuf[w][lane] = h;
    __syncthreads();
    if (active) {
        float y = b_lin[lane];
        #pragma unroll 8
        for (int c = 0; c < 64; ++c)
            y = fmaf(WT[c * 65 + lane], hbuf[w][c], y);
        out[(size_t)node * 64 + lane] = y;
    }
}

extern "C" void kernel_launch(void* const* d_in, const int* in_sizes, int n_in,
                              void* d_out, int out_size, void* d_ws, size_t ws_size,
                              hipStream_t stream) {
    const float* x      = (const float*)d_in[0];
    const int*   ei     = (const int*)d_in[1];
    // d_in[2] = edge_weight: unused by the reference
    const float* W_l    = (const float*)d_in[3];
    const float* W_r    = (const float*)d_in[4];
    const float* att    = (const float*)d_in[5];
    const float* bias_c = (const float*)d_in[6];
    const float* W_lin  = (const float*)d_in[7];
    const float* b_lin  = (const float*)d_in[8];
    float* out = (float*)d_out;

    int N = in_sizes[0] / IN_CH;
    int E = in_sizes[2];
    const int* srcp = ei;
    const int* dstp = ei + E;

    int NP = ((N + 4095) / 4096) * 4096;   // padded for int4 scan

    char* ws = (char*)d_ws;
    float* xl = (float*)ws;
    float* xr = xl + (size_t)N * HID;
    int* deg       = (int*)(xr + (size_t)N * HID);
    int* row_start = deg + NP;
    int* cursor    = row_start + NP;
    int* csr       = cursor + NP;

    hipMemsetAsync(deg, 0, (size_t)NP * sizeof(int), stream);
    proj_kernel<<<512, 256, 0, stream>>>(x, W_l, W_r, xl, xr, N);
    hist_kernel<<<(E + 255) / 256, 256, 0, stream>>>(dstp, deg, E);
    scan_kernel<<<1, 1024, 0, stream>>>(deg, row_start, cursor, NP);
    scatter_kernel<<<(E + 255) / 256, 256, 0, stream>>>(srcp, dstp, cursor, csr, E);
    gat_main<<<(N + 3) / 4, 256, 0, stream>>>(xl, xr, row_start, cursor, csr,
                                              att, bias_c, W_lin, b_lin, out, N);
}

// Round 2
// 415.918 us; speedup vs baseline: 1.0703x; 1.0703x over previous
//
#include <hip/hip_runtime.h>

#define IN_CH 128
#define HID 64
#define NEG 0.2f

// ---------------- K1: projections xl = x@W_l.T, xr = x@W_r.T ----------------
__global__ __launch_bounds__(256) void proj_kernel(
    const float* __restrict__ x, const float* __restrict__ W_l,
    const float* __restrict__ W_r,
    float* __restrict__ xl, float* __restrict__ xr, int nN)
{
    __shared__ float Ws[64 * 132];
    __shared__ float x_s[4 * IN_CH];
    int tid = threadIdx.x;
    int lane = tid & 63, w = tid >> 6;

    for (int m = 0; m < 2; ++m) {
        const float* __restrict__ W = m ? W_r : W_l;
        float* __restrict__ dstv = m ? xr : xl;
        __syncthreads();  // protect Ws from previous phase readers
        for (int idx = tid; idx < 64 * IN_CH; idx += 256) {
            int c = idx >> 7, k = idx & 127;
            Ws[c * 132 + k] = W[idx];
        }
        __syncthreads();
        for (int nb = blockIdx.x * 4; nb < nN; nb += gridDim.x * 4) {
            int node = nb + w;
            if (node < nN) {
                float2 xv = *(const float2*)(x + (size_t)node * IN_CH + lane * 2);
                x_s[w * IN_CH + lane * 2]     = xv.x;
                x_s[w * IN_CH + lane * 2 + 1] = xv.y;
            }
            __syncthreads();
            if (node < nN) {
                float a0 = 0.f, a1 = 0.f, a2 = 0.f, a3 = 0.f;
                const float4* xs4 = (const float4*)(x_s + w * IN_CH);
                const float4* w4  = (const float4*)(Ws + lane * 132);
                #pragma unroll
                for (int k4 = 0; k4 < 32; k4 += 4) {
                    float4 xv0 = xs4[k4+0], wv0 = w4[k4+0];
                    a0 = fmaf(xv0.x, wv0.x, a0); a0 = fmaf(xv0.y, wv0.y, a0);
                    a0 = fmaf(xv0.z, wv0.z, a0); a0 = fmaf(xv0.w, wv0.w, a0);
                    float4 xv1 = xs4[k4+1], wv1 = w4[k4+1];
                    a1 = fmaf(xv1.x, wv1.x, a1); a1 = fmaf(xv1.y, wv1.y, a1);
                    a1 = fmaf(xv1.z, wv1.z, a1); a1 = fmaf(xv1.w, wv1.w, a1);
                    float4 xv2 = xs4[k4+2], wv2 = w4[k4+2];
                    a2 = fmaf(xv2.x, wv2.x, a2); a2 = fmaf(xv2.y, wv2.y, a2);
                    a2 = fmaf(xv2.z, wv2.z, a2); a2 = fmaf(xv2.w, wv2.w, a2);
                    float4 xv3 = xs4[k4+3], wv3 = w4[k4+3];
                    a3 = fmaf(xv3.x, wv3.x, a3); a3 = fmaf(xv3.y, wv3.y, a3);
                    a3 = fmaf(xv3.z, wv3.z, a3); a3 = fmaf(xv3.w, wv3.w, a3);
                }
                dstv[(size_t)node * HID + lane] = (a0 + a1) + (a2 + a3);
            }
            __syncthreads();
        }
    }
}

// ---------------- K2: in-degree histogram (4 edges/thread) ----------------
__global__ __launch_bounds__(256) void hist_kernel(
    const int* __restrict__ dst, int* __restrict__ deg, int E)
{
    int i = (blockIdx.x * 256 + threadIdx.x) * 4;
    if (i + 3 < E) {
        int4 v = *(const int4*)(dst + i);
        atomicAdd(&deg[v.x], 1);
        atomicAdd(&deg[v.y], 1);
        atomicAdd(&deg[v.z], 1);
        atomicAdd(&deg[v.w], 1);
    } else {
        for (; i < E; ++i) atomicAdd(&deg[dst[i]], 1);
    }
}

// ---------------- K3: exclusive scan (single block, int4 chunks of 4096) ----
__global__ __launch_bounds__(1024) void scan_kernel(
    const int* __restrict__ deg, int* __restrict__ row_start,
    int* __restrict__ cursor, int np)
{
    __shared__ int wsum[16];
    __shared__ int running_s;
    int tid = threadIdx.x, lane = tid & 63, w = tid >> 6;
    if (tid == 0) running_s = 0;
    __syncthreads();
    for (int base = 0; base < np; base += 4096) {
        int i = base + tid * 4;
        int4 v = *(const int4*)(deg + i);
        int p0 = v.x, p1 = p0 + v.y, p2 = p1 + v.z, p3 = p2 + v.w;
        int sv = p3;
        #pragma unroll
        for (int d = 1; d < 64; d <<= 1) {
            int t = __shfl_up(sv, d, 64);
            if (lane >= d) sv += t;
        }
        if (lane == 63) wsum[w] = sv;
        __syncthreads();
        if (tid < 16) {
            int t = wsum[tid];
            #pragma unroll
            for (int d = 1; d < 16; d <<= 1) {
                int u = __shfl_up(t, d, 64);
                if (tid >= d) t += u;
            }
            wsum[tid] = t;
        }
        __syncthreads();
        int run0 = running_s;
        int excl = run0 + (w ? wsum[w - 1] : 0) + sv - p3;  // thread-exclusive
        int4 o = make_int4(excl, excl + p0, excl + p1, excl + p2);
        *(int4*)(row_start + i) = o;
        *(int4*)(cursor + i) = o;
        __syncthreads();
        if (tid == 0) running_s = run0 + wsum[15];
        __syncthreads();
    }
}

// ---------------- K4: scatter edges into CSR slots (4 edges/thread) --------
__global__ __launch_bounds__(256) void scatter_kernel(
    const int* __restrict__ src, const int* __restrict__ dst,
    int* __restrict__ cursor, int* __restrict__ csr, int E)
{
    int i = (blockIdx.x * 256 + threadIdx.x) * 4;
    if (i + 3 < E) {
        int4 sv = *(const int4*)(src + i);
        int4 dv = *(const int4*)(dst + i);
        int p0 = atomicAdd(&cursor[dv.x], 1); csr[p0] = sv.x;
        int p1 = atomicAdd(&cursor[dv.y], 1); csr[p1] = sv.y;
        int p2 = atomicAdd(&cursor[dv.z], 1); csr[p2] = sv.z;
        int p3 = atomicAdd(&cursor[dv.w], 1); csr[p3] = sv.w;
    } else {
        for (; i < E; ++i) {
            int p = atomicAdd(&cursor[dst[i]], 1);
            csr[p] = src[i];
        }
    }
}

// ---------------- K5: fused attention + aggregation + ELU + linear ----------
// One wave per node; wave splits into 4 groups x 16 lanes; lane = 4 channels.
// Each group processes one edge per batch -> 1 dwordx4 load covers 4 edges.
__global__ __launch_bounds__(256) void gat_main(
    const float* __restrict__ xl, const float* __restrict__ xr,
    const int* __restrict__ row_start, const int* __restrict__ row_end,
    const int* __restrict__ csr,
    const float* __restrict__ att, const float* __restrict__ bias_conv,
    const float* __restrict__ W_lin, const float* __restrict__ b_lin,
    float* __restrict__ out, int nN)
{
    __shared__ float WT[64 * 65];   // WT[c*65+o] = W_lin[o][c], +1 pad
    __shared__ float hbuf[4][64];
    int tid = threadIdx.x;
    for (int idx = tid; idx < 64 * 64; idx += 256) {
        int o = idx >> 6, c = idx & 63;
        WT[c * 65 + o] = W_lin[idx];
    }
    int lane = tid & 63, w = tid >> 6;
    int g = lane >> 4, gl = lane & 15;
    int node = blockIdx.x * 4 + w;
    bool active = node < nN;
    if (active) {
        const float4 att4 = *(const float4*)(att + gl * 4);
        const float4 xr4  = *(const float4*)(xr + (size_t)node * HID + gl * 4);
        float4 acc = make_float4(0.f, 0.f, 0.f, 0.f);
        float denom = 0.f;
        // self loop: group 0 only
        if (g == 0) {
            float4 xs = *(const float4*)(xl + (size_t)node * HID + gl * 4);
            float tx = xs.x + xr4.x, ty = xs.y + xr4.y;
            float tz = xs.z + xr4.z, tw = xs.w + xr4.w;
            float lx = fmaxf(tx, 0.f) + NEG * fminf(tx, 0.f);
            float ly = fmaxf(ty, 0.f) + NEG * fminf(ty, 0.f);
            float lz = fmaxf(tz, 0.f) + NEG * fminf(tz, 0.f);
            float lw = fmaxf(tw, 0.f) + NEG * fminf(tw, 0.f);
            float r = att4.x * lx;
            r = fmaf(att4.y, ly, r); r = fmaf(att4.z, lz, r); r = fmaf(att4.w, lw, r);
            r += __shfl_xor(r, 1, 64);
            r += __shfl_xor(r, 2, 64);
            r += __shfl_xor(r, 4, 64);
            r += __shfl_xor(r, 8, 64);
            float ev = __expf(r);
            denom = ev;
            acc.x = ev * xs.x; acc.y = ev * xs.y;
            acc.z = ev * xs.z; acc.w = ev * xs.w;
        }
        int s = row_start[node], e = row_end[node];
        for (int base = s; base < e; base += 4) {
            int k = base + g;
            int kc = (k < e) ? k : (e - 1);
            int j = csr[kc];
            float4 xj = *(const float4*)(xl + (size_t)j * HID + gl * 4);
            float tx = xj.x + xr4.x, ty = xj.y + xr4.y;
            float tz = xj.z + xr4.z, tw = xj.w + xr4.w;
            float lx = fmaxf(tx, 0.f) + NEG * fminf(tx, 0.f);
            float ly = fmaxf(ty, 0.f) + NEG * fminf(ty, 0.f);
            float lz = fmaxf(tz, 0.f) + NEG * fminf(tz, 0.f);
            float lw = fmaxf(tw, 0.f) + NEG * fminf(tw, 0.f);
            float r = att4.x * lx;
            r = fmaf(att4.y, ly, r); r = fmaf(att4.z, lz, r); r = fmaf(att4.w, lw, r);
            r += __shfl_xor(r, 1, 64);
            r += __shfl_xor(r, 2, 64);
            r += __shfl_xor(r, 4, 64);
            r += __shfl_xor(r, 8, 64);
            float ev = __expf(r);
            if (k >= e) ev = 0.f;
            denom += ev;
            acc.x = fmaf(ev, xj.x, acc.x);
            acc.y = fmaf(ev, xj.y, acc.y);
            acc.z = fmaf(ev, xj.z, acc.z);
            acc.w = fmaf(ev, xj.w, acc.w);
        }
        // cross-group combine (4 groups hold partials for the same channels)
        denom += __shfl_xor(denom, 16, 64);
        denom += __shfl_xor(denom, 32, 64);
        acc.x += __shfl_xor(acc.x, 16, 64); acc.x += __shfl_xor(acc.x, 32, 64);
        acc.y += __shfl_xor(acc.y, 16, 64); acc.y += __shfl_xor(acc.y, 32, 64);
        acc.z += __shfl_xor(acc.z, 16, 64); acc.z += __shfl_xor(acc.z, 32, 64);
        acc.w += __shfl_xor(acc.w, 16, 64); acc.w += __shfl_xor(acc.w, 32, 64);
        float inv = 1.f / (denom + 1e-16f);
        float4 b4 = *(const float4*)(bias_conv + gl * 4);
        float hx = fmaf(acc.x, inv, b4.x);
        float hy = fmaf(acc.y, inv, b4.y);
        float hz = fmaf(acc.z, inv, b4.z);
        float hw = fmaf(acc.w, inv, b4.w);
        hx = (hx > 0.f) ? hx : (__expf(hx) - 1.f);
        hy = (hy > 0.f) ? hy : (__expf(hy) - 1.f);
        hz = (hz > 0.f) ? hz : (__expf(hz) - 1.f);
        hw = (hw > 0.f) ? hw : (__expf(hw) - 1.f);
        if (g == 0) {
            *(float4*)(&hbuf[w][gl * 4]) = make_float4(hx, hy, hz, hw);
        }
    }
    __syncthreads();   // covers WT staging + hbuf writes
    if (active) {
        float y = b_lin[lane];
        #pragma unroll 8
        for (int c = 0; c < 64; ++c)
            y = fmaf(WT[c * 65 + lane], hbuf[w][c], y);
        out[(size_t)node * 64 + lane] = y;
    }
}

extern "C" void kernel_launch(void* const* d_in, const int* in_sizes, int n_in,
                              void* d_out, int out_size, void* d_ws, size_t ws_size,
                              hipStream_t stream) {
    const float* x      = (const float*)d_in[0];
    const int*   ei     = (const int*)d_in[1];
    // d_in[2] = edge_weight: unused by the reference
    const float* W_l    = (const float*)d_in[3];
    const float* W_r    = (const float*)d_in[4];
    const float* att    = (const float*)d_in[5];
    const float* bias_c = (const float*)d_in[6];
    const float* W_lin  = (const float*)d_in[7];
    const float* b_lin  = (const float*)d_in[8];
    float* out = (float*)d_out;

    int N = in_sizes[0] / IN_CH;
    int E = in_sizes[2];
    const int* srcp = ei;
    const int* dstp = ei + E;

    int NP = ((N + 4095) / 4096) * 4096;   // padded for int4 scan

    char* ws = (char*)d_ws;
    float* xl = (float*)ws;
    float* xr = xl + (size_t)N * HID;
    int* deg       = (int*)(xr + (size_t)N * HID);
    int* row_start = deg + NP;
    int* cursor    = row_start + NP;
    int* csr       = cursor + NP;

    hipMemsetAsync(deg, 0, (size_t)NP * sizeof(int), stream);
    proj_kernel<<<1024, 256, 0, stream>>>(x, W_l, W_r, xl, xr, N);
    hist_kernel<<<(E / 4 + 255) / 256, 256, 0, stream>>>(dstp, deg, E);
    scan_kernel<<<1, 1024, 0, stream>>>(deg, row_start, cursor, NP);
    scatter_kernel<<<(E / 4 + 255) / 256, 256, 0, stream>>>(srcp, dstp, cursor, csr, E);
    gat_main<<<(N + 3) / 4, 256, 0, stream>>>(xl, xr, row_start, cursor, csr,
                                              att, bias_c, W_lin, b_lin, out, N);
}